// Round 7
// baseline (422.839 us; speedup 1.0000x reference)
//
#include <hip/hip_runtime.h>
#include <cstdint>
#include <cstddef>

// IT_Fast_Attn: B=8, C=256, N=4096, 2 iterations. fp32 I/O, bf16 compute.
// Round 7 = round 6 design with the staging-address fix: loadRaw must index
// (rowBase + rloc + sRow), not (rowBase + rloc). r6 dropped sRow -> absmax 8.6.
//   xt = transpose(x) bf16 ; W* -> bf16
//   Xb = xt @ Wqkv^T ; XT = transpose(Xb)
//   loop 2x (Vcur=Xb, VTcur=XT on iter 0):
//     smstats: per-row {max, 1/sumexp} of Xb
//     ctxT = split-K(16) VT@XT partials -> reduce -> ctxb bf16
//     OUT  = softmax(Xb) @ ctxT^T      (exp applied in A-staging)
//     MLPo = relu([OUT|Vcur] @ Wmlp^T + b)   (2-source A)
//     stats1024: per-row {mean, rstd} of [OUT|Vcur|MLPo]
//     Tb   = LN1024([OUT|Vcur|MLPo]) @ Wres^T + 2*Xb  (LN in A-staging)
//     Vb   = LN256(Tb); VT = transpose (fused); last iter -> d_out fp32

using u16 = unsigned short;
using short8 = __attribute__((ext_vector_type(8))) short;
using bf16x8 = __attribute__((ext_vector_type(8))) __bf16;
using f32x4  = __attribute__((ext_vector_type(4))) float;
using i32x4  = __attribute__((ext_vector_type(4))) int;
using u16x4  = __attribute__((ext_vector_type(4))) u16;
using u16x8  = __attribute__((ext_vector_type(8))) u16;

__device__ __forceinline__ float b2f(u16 u) {
    union { unsigned u32; float f; } c; c.u32 = ((unsigned)u) << 16; return c.f;
}
__device__ __forceinline__ u16 f2b(float f) {
    union { float f; unsigned u; } c; c.f = f;
    unsigned r = c.u + 0x7FFFu + ((c.u >> 16) & 1u);
    return (u16)(r >> 16);
}
__device__ __forceinline__ void cvt(u16 a,  u16& o)   { o = a; }
__device__ __forceinline__ void cvt(float a, u16& o)  { o = f2b(a); }
__device__ __forceinline__ void cvt(float a, float& o){ o = a; }
__device__ __forceinline__ void cvt(u16 a,  float& o) { o = b2f(a); }

// ---------------------------------------------------------------------------
// BT GEMM: C[row,col] = sum_k A[row,k] * B[col,k].  BM=BN=128, BK=32.
// COL-fastest grid (colBase=blockIdx.x): r3-measured L2 A-reuse.
// TRF (A-staging transform):
//   0 = plain copy            1 = softmax: a'=exp(a-st.x)*st.y
//   2 = LN1024 affine over 3 sources (A|A2|A3, region=k>>8):
//       a'=(a-st.x)*st.y*g[k]+be[k]
//   3 = 2-source split at kSplit (MLP [OUT|V]), no transform
// MODE (epilogue): 0 = store bf16; 1 = fp32 partial per ks-slice;
//   3 = +bias, relu, bf16; 4 = +2*Xres(bf16), bf16.
// ---------------------------------------------------------------------------
template<int MODE, int TRF>
__global__ __launch_bounds__(256)
void gemm_bt(const u16* __restrict__ A, const u16* __restrict__ A2,
             const u16* __restrict__ A3,
             int lda, int lda2, int lda3, int kSplit,
             const u16* __restrict__ B, int ldb, long strA, long strB,
             int statStride, int kChunk, int nKsplit,
             float* __restrict__ outF, u16* __restrict__ outB,
             long sOF, long sOB, int ldo,
             const u16* __restrict__ Xres,
             const float* __restrict__ bias,
             const float2* __restrict__ stats,
             const float* __restrict__ g, const float* __restrict__ be)
{
    __shared__ short lsA[128 * 40];
    __shared__ short lsB[128 * 40];

    const int bz    = blockIdx.z;
    const int batch = bz / nKsplit;
    const int ks    = bz - batch * nKsplit;
    const u16* Ab = A + (size_t)batch * strA;
    const u16* Bb = B + (size_t)batch * strB;
    const int colBase = blockIdx.x * 128;   // col-fastest
    const int rowBase = blockIdx.y * 128;
    const int k0 = ks * kChunk;
    const int k1 = k0 + kChunk;

    const int t    = threadIdx.x;
    const int sRow = t >> 2;           // 0..63
    const int sKq  = (t & 3) << 3;     // 0,8,16,24

    const int lane = t & 63;
    const int wave = t >> 6;
    const int wr   = (wave >> 1) * 64;
    const int wc   = (wave & 1) * 64;
    const int mrow = lane & 15;
    const int q    = lane >> 4;

    float2 st0 = {0.f, 0.f}, st1 = {0.f, 0.f};
    if (TRF == 1 || TRF == 2) {
        const int sb = batch * statStride + rowBase;
        st0 = stats[sb + sRow];
        st1 = stats[sb + sRow + 64];
    }

    // raw A load for staged row (rowBase + rloc + sRow) at k-base kn
    auto loadRaw = [&](int rloc, int kn) -> i32x4 {
        const int arow = rowBase + rloc + sRow;   // r6 BUG was missing sRow
        if (TRF == 2) {
            const u16* s; int ld; int kl;
            const int reg = kn >> 8;
            if (reg == 0)      { s = A;  ld = lda;  kl = kn; }
            else if (reg == 1) { s = A2; ld = lda2; kl = kn - 256; }
            else               { s = A3; ld = lda3; kl = kn - 512; }
            return *(const i32x4*)(s + (size_t)arow * ld + kl + sKq);
        } else if (TRF == 3) {
            if (kn < kSplit)
                return *(const i32x4*)(Ab + (size_t)arow * lda + kn + sKq);
            return *(const i32x4*)(A2 + (size_t)arow * lda2 + (kn - kSplit) + sKq);
        }
        return *(const i32x4*)(Ab + (size_t)arow * lda + kn + sKq);
    };
    auto xform = [&](i32x4 raw, float2 st, int kn) -> i32x4 {
        if (TRF == 0 || TRF == 3) return raw;
        short8 h = __builtin_bit_cast(short8, raw);
        short8 o;
#pragma unroll
        for (int i = 0; i < 8; i++) {
            float v = b2f((u16)h[i]);
            if (TRF == 1) v = __expf(v - st.x) * st.y;
            else          v = (v - st.x) * st.y * g[kn + sKq + i] + be[kn + sKq + i];
            o[i] = (short)f2b(v);
        }
        return __builtin_bit_cast(i32x4, o);
    };

    const f32x4 fzero = {0.f, 0.f, 0.f, 0.f};
    f32x4 acc[4][4];
#pragma unroll
    for (int i = 0; i < 4; i++)
#pragma unroll
        for (int j = 0; j < 4; j++) acc[i][j] = fzero;

    const u16* pB0 = Bb + (size_t)(colBase + sRow) * ldb + sKq;
    const u16* pB1 = pB0 + (size_t)64 * ldb;

    i32x4 a0 = xform(loadRaw(0,  k0), st0, k0);
    i32x4 a1 = xform(loadRaw(64, k0), st1, k0);
    i32x4 b0 = *(const i32x4*)(pB0 + k0);
    i32x4 b1 = *(const i32x4*)(pB1 + k0);

    for (int kk = k0; kk < k1; kk += 32) {
        __syncthreads();
        *(i32x4*)&lsA[sRow * 40 + sKq]        = a0;
        *(i32x4*)&lsA[(sRow + 64) * 40 + sKq] = a1;
        *(i32x4*)&lsB[sRow * 40 + sKq]        = b0;
        *(i32x4*)&lsB[(sRow + 64) * 40 + sKq] = b1;
        __syncthreads();
        const int kn = kk + 32;
        if (kn < k1) {
            a0 = xform(loadRaw(0,  kn), st0, kn);
            a1 = xform(loadRaw(64, kn), st1, kn);
            b0 = *(const i32x4*)(pB0 + kn);
            b1 = *(const i32x4*)(pB1 + kn);
        }
        bf16x8 af[4], bfr[4];
#pragma unroll
        for (int mi = 0; mi < 4; mi++)
            af[mi] = __builtin_bit_cast(bf16x8,
                *(const short8*)&lsA[(wr + mi * 16 + mrow) * 40 + q * 8]);
#pragma unroll
        for (int ni = 0; ni < 4; ni++)
            bfr[ni] = __builtin_bit_cast(bf16x8,
                *(const short8*)&lsB[(wc + ni * 16 + mrow) * 40 + q * 8]);
#pragma unroll
        for (int mi = 0; mi < 4; mi++)
#pragma unroll
            for (int ni = 0; ni < 4; ni++)
                acc[mi][ni] = __builtin_amdgcn_mfma_f32_16x16x32_bf16(
                    af[mi], bfr[ni], acc[mi][ni], 0, 0, 0);
    }

    // epilogue: lane holds D[row = q*4+r][col = mrow] per 16x16 tile
#pragma unroll
    for (int mi = 0; mi < 4; mi++) {
#pragma unroll
        for (int ni = 0; ni < 4; ni++) {
            const int col = colBase + wc + ni * 16 + mrow;
#pragma unroll
            for (int r = 0; r < 4; r++) {
                const int row = rowBase + wr + mi * 16 + q * 4 + r;
                float v = acc[mi][ni][r];
                if (MODE == 0) {
                    outB[(size_t)batch * sOB + (size_t)row * ldo + col] = f2b(v);
                } else if (MODE == 1) {
                    outF[((size_t)batch * nKsplit + ks) * sOF
                         + (size_t)row * ldo + col] = v;
                } else if (MODE == 3) {
                    v += bias[col];
                    v = v > 0.f ? v : 0.f;
                    outB[(size_t)row * ldo + col] = f2b(v);
                } else if (MODE == 4) {
                    v += 2.f * b2f(Xres[(size_t)row * 256 + col]);
                    outB[(size_t)row * ldo + col] = f2b(v);
                }
            }
        }
    }
}

// ---------------------------------------------------------------------------
// Transpose (R x Cc) -> (Cc x R) per batch, with dtype conversion.
// ---------------------------------------------------------------------------
template<typename TIN, typename TOUT>
__global__ __launch_bounds__(256)
void transpose_k(const TIN* __restrict__ in, TOUT* __restrict__ out,
                 int R, int Cc, long sIn, long sOut)
{
    __shared__ TOUT tile[32][33];
    const int b = blockIdx.z;
    const TIN* ib = in + (size_t)b * sIn;
    TOUT* ob = out + (size_t)b * sOut;
    const int c0 = blockIdx.x * 32, r0 = blockIdx.y * 32;
    const int tx = threadIdx.x & 31, ty = threadIdx.x >> 5;
#pragma unroll
    for (int i = 0; i < 32; i += 8)
        cvt(ib[(size_t)(r0 + ty + i) * Cc + c0 + tx], tile[ty + i][tx]);
    __syncthreads();
#pragma unroll
    for (int i = 0; i < 32; i += 8)
        ob[(size_t)(c0 + ty + i) * R + r0 + tx] = tile[tx][ty + i];
}

// Per-row softmax stats of Xb (rows of 256): {max, 1/sumexp}. One wave/row.
__global__ __launch_bounds__(256)
void smstats_k(const u16* __restrict__ Xb, float2* __restrict__ st)
{
    const int wave = threadIdx.x >> 6, lane = threadIdx.x & 63;
    const size_t row = (size_t)blockIdx.x * 4 + wave;
    const u16x4 xb = *(const u16x4*)(Xb + row * 256 + lane * 4);
    const float x0 = b2f(xb.x), x1 = b2f(xb.y), x2 = b2f(xb.z), x3 = b2f(xb.w);
    float m = fmaxf(fmaxf(x0, x1), fmaxf(x2, x3));
    for (int o = 32; o > 0; o >>= 1) m = fmaxf(m, __shfl_xor(m, o));
    float s = __expf(x0 - m) + __expf(x1 - m) + __expf(x2 - m) + __expf(x3 - m);
    for (int o = 32; o > 0; o >>= 1) s += __shfl_xor(s, o);
    if (lane == 0) st[row] = make_float2(m, 1.f / s);
}

// Per-row LN stats of virtual row [OUT(256)|V(256)|MLPo(512)]: {mean, rstd}.
__global__ __launch_bounds__(256)
void stats1024_k(const u16* __restrict__ OUT, const u16* __restrict__ V,
                 const u16* __restrict__ MLPo, float2* __restrict__ st)
{
    const int wave = threadIdx.x >> 6, lane = threadIdx.x & 63;
    const size_t row = (size_t)blockIdx.x * 4 + wave;
    const int c = lane * 16;
    const u16* src;
    if (c < 256)       src = OUT  + row * 256 + c;
    else if (c < 512)  src = V    + row * 256 + (c - 256);
    else               src = MLPo + row * 512 + (c - 512);
    short8 r0 = *(const short8*)(src);
    short8 r1 = *(const short8*)(src + 8);
    float s = 0.f, s2 = 0.f;
#pragma unroll
    for (int i = 0; i < 8; i++) {
        const float a = b2f((u16)r0[i]), b = b2f((u16)r1[i]);
        s += a + b; s2 += a * a + b * b;
    }
    for (int o = 32; o > 0; o >>= 1) { s += __shfl_xor(s, o); s2 += __shfl_xor(s2, o); }
    const float mean = s * (1.f / 1024.f);
    const float var  = s2 * (1.f / 1024.f) - mean * mean;
    if (lane == 0) st[row] = make_float2(mean, rsqrtf(var + 1e-5f));
}

// ---------------------------------------------------------------------------
// Fused LN256 + transpose (unchanged from r5).
// ---------------------------------------------------------------------------
template<typename OUTT, bool WRITE_VB>
__global__ __launch_bounds__(256)
void ln256t_k(const u16* __restrict__ Tb, const float* __restrict__ g,
              const float* __restrict__ be, u16* __restrict__ Vb,
              OUTT* __restrict__ outT)
{
    constexpr int STRIDE = (sizeof(OUTT) == 2) ? 266 : 261;
    __shared__ OUTT tile[32 * STRIDE];
    const int wid = threadIdx.x >> 6, lane = threadIdx.x & 63;
    const int bx = blockIdx.x;
    const size_t r0 = (size_t)bx * 32;
    const int b  = bx >> 7;
    const int n0 = (bx & 127) * 32;

#pragma unroll
    for (int j = 0; j < 8; j++) {
        const int lr = wid * 8 + j;
        const size_t row = r0 + lr;
        const u16x4 tb = *(const u16x4*)(Tb + row * 256 + lane * 4);
        const float x0 = b2f(tb.x), x1 = b2f(tb.y), x2 = b2f(tb.z), x3 = b2f(tb.w);
        float s  = x0 + x1 + x2 + x3;
        float s2 = x0 * x0 + x1 * x1 + x2 * x2 + x3 * x3;
        for (int o = 32; o > 0; o >>= 1) { s += __shfl_xor(s, o); s2 += __shfl_xor(s2, o); }
        const float mean = s * (1.f / 256.f);
        const float var  = s2 * (1.f / 256.f) - mean * mean;
        const float rstd = rsqrtf(var + 1e-5f);
        const int c = lane * 4;
        float4 ov = { (x0 - mean) * rstd * g[c + 0] + be[c + 0],
                      (x1 - mean) * rstd * g[c + 1] + be[c + 1],
                      (x2 - mean) * rstd * g[c + 2] + be[c + 2],
                      (x3 - mean) * rstd * g[c + 3] + be[c + 3] };
        if (WRITE_VB) {
            u16x4 vb = { f2b(ov.x), f2b(ov.y), f2b(ov.z), f2b(ov.w) };
            *(u16x4*)(Vb + row * 256 + c) = vb;
        }
        OUTT* tl = &tile[lr * STRIDE + c];
        cvt(ov.x, tl[0]); cvt(ov.y, tl[1]); cvt(ov.z, tl[2]); cvt(ov.w, tl[3]);
    }
    __syncthreads();

    const int c = threadIdx.x;
    OUTT* dst = outT + ((size_t)b * 256 + c) * 4096 + n0;
    if (sizeof(OUTT) == 2) {
#pragma unroll
        for (int k = 0; k < 4; k++) {
            u16x8 v;
#pragma unroll
            for (int i = 0; i < 8; i++) v[i] = *(const u16*)&tile[(k * 8 + i) * STRIDE + c];
            *(u16x8*)((u16*)dst + k * 8) = v;
        }
    } else {
#pragma unroll
        for (int k = 0; k < 8; k++) {
            float4 v;
            v.x = *(const float*)&tile[(k * 4 + 0) * STRIDE + c];
            v.y = *(const float*)&tile[(k * 4 + 1) * STRIDE + c];
            v.z = *(const float*)&tile[(k * 4 + 2) * STRIDE + c];
            v.w = *(const float*)&tile[(k * 4 + 3) * STRIDE + c];
            *(float4*)((float*)dst + k * 4) = v;
        }
    }
}

// Reduce 16 split-K partial fp32 ctx buffers -> bf16.
__global__ __launch_bounds__(256)
void ctxreduce_k(const float* __restrict__ ctxp, u16* __restrict__ ctxb)
{
    const int i = blockIdx.x * 256 + threadIdx.x;
    const int batch  = i >> 14;
    const int within = i & 16383;
    const float4* src = (const float4*)ctxp + (size_t)batch * 16 * 16384 + within;
    float4 s = {0.f, 0.f, 0.f, 0.f};
#pragma unroll
    for (int ks = 0; ks < 16; ks++) {
        const float4 v = src[(size_t)ks * 16384];
        s.x += v.x; s.y += v.y; s.z += v.z; s.w += v.w;
    }
    u16x4 o = { f2b(s.x), f2b(s.y), f2b(s.z), f2b(s.w) };
    ((u16x4*)ctxb)[i] = o;
}

// Convert three weight matrices fp32->bf16 in one launch.
__global__ __launch_bounds__(256)
void wconv_k(const float* __restrict__ Wq, const float* __restrict__ Wm,
             const float* __restrict__ Wr, u16* __restrict__ oq,
             u16* __restrict__ om, u16* __restrict__ orr)
{
    const int i = blockIdx.x * 256 + threadIdx.x;
    const float* src; u16* dst; int j;
    if (i < 16384)      { src = Wq; dst = oq;  j = i; }
    else if (i < 81920) { src = Wm; dst = om;  j = i - 16384; }
    else                { src = Wr; dst = orr; j = i - 81920; }
    const float4 v = ((const float4*)src)[j];
    u16x4 o = { f2b(v.x), f2b(v.y), f2b(v.z), f2b(v.w) };
    ((u16x4*)dst)[j] = o;
}

extern "C" void kernel_launch(void* const* d_in, const int* in_sizes, int n_in,
                              void* d_out, int out_size, void* d_ws, size_t ws_size,
                              hipStream_t stream)
{
    (void)in_sizes; (void)n_in; (void)out_size; (void)ws_size;
    const float* x    = (const float*)d_in[0];
    const float* Wqkv = (const float*)d_in[1];
    const float* Wmlp = (const float*)d_in[2];
    const float* bmlp = (const float*)d_in[3];
    const float* g1   = (const float*)d_in[4];
    const float* be1  = (const float*)d_in[5];
    const float* Wres = (const float*)d_in[6];
    const float* g2   = (const float*)d_in[7];
    const float* be2  = (const float*)d_in[8];

    // workspace (~172 MiB of 256)
    char* ws = (char*)d_ws;
    u16*    Xb   = (u16*)ws;    ws += (size_t)16777216;   // (32768,256)
    u16*    XT   = (u16*)ws;    ws += (size_t)16777216;   // (B,256,4096)
    u16*    Vb   = (u16*)ws;    ws += (size_t)16777216;   // (32768,256)
    u16*    VT2  = (u16*)ws;    ws += (size_t)16777216;   // (B,256,4096)
    u16*    OUT  = (u16*)ws;    ws += (size_t)16777216;   // (32768,256)
    u16*    MLPo = (u16*)ws;    ws += (size_t)33554432;   // (32768,512)
    u16*    Tb   = (u16*)ws;    ws += (size_t)16777216;   // (32768,256)
    float*  ctxp = (float*)ws;  ws += (size_t)33554432;   // (B*16,256,256) fp32
    u16*    ctxb = (u16*)ws;    ws += (size_t)1048576;    // (B,256,256)
    float2* smst = (float2*)ws; ws += (size_t)262144;     // (32768) {max,1/s}
    float2* lnst = (float2*)ws; ws += (size_t)262144;     // (32768) {mean,rstd}
    u16*    Wq_b = (u16*)ws;    ws += (size_t)131072;
    u16*    Wm_b = (u16*)ws;    ws += (size_t)524288;
    u16*    Wr_b = (u16*)ws;    ws += (size_t)524288;
    u16*    xt   = MLPo;  // alias: xt dead before MLPo's first write

    // 0. weights fp32 -> bf16
    wconv_k<<<dim3(576), 256, 0, stream>>>(Wqkv, Wmlp, Wres, Wq_b, Wm_b, Wr_b);

    // 1. xt = transpose(x): per batch (256,4096) fp32 -> (4096,256) bf16
    transpose_k<float, u16><<<dim3(128, 8, 8), 256, 0, stream>>>(
        x, xt, 256, 4096, 256L * 4096, 4096L * 256);

    // 2. Xb = xt @ Wqkv^T   [M=32768,N=256,K=256]
    gemm_bt<0, 0><<<dim3(2, 256, 1), 256, 0, stream>>>(
        xt, nullptr, nullptr, 256, 0, 0, 0, Wq_b, 256, 0, 0, 0, 256, 1,
        nullptr, Xb, 0, 0, 256, nullptr, nullptr, nullptr, nullptr, nullptr);

    // 3. XT = transpose(Xb)
    transpose_k<u16, u16><<<dim3(8, 128, 8), 256, 0, stream>>>(
        Xb, XT, 4096, 256, 4096L * 256, 256L * 4096);

    const u16* VTcur = XT;
    const u16* Vcur  = Xb;

    for (int it = 0; it < 2; ++it) {
        // softmax stats
        smstats_k<<<dim3(8192), 256, 0, stream>>>(Xb, smst);

        // ctx split-K=16 partials
        gemm_bt<1, 0><<<dim3(2, 2, 128), 256, 0, stream>>>(
            VTcur, nullptr, nullptr, 4096, 0, 0, 0, XT, 4096,
            1048576, 1048576, 0, 256, 16,
            ctxp, nullptr, 65536, 0, 256, nullptr, nullptr, nullptr, nullptr, nullptr);
        ctxreduce_k<<<dim3(512), 256, 0, stream>>>(ctxp, ctxb);

        // OUT = softmax(Xb) @ ctxT^T  (exp in staging) [per batch 4096x256,K=256]
        gemm_bt<0, 1><<<dim3(2, 32, 8), 256, 0, stream>>>(
            Xb, nullptr, nullptr, 256, 0, 0, 0, ctxb, 256,
            1048576, 65536, 4096, 256, 1,
            nullptr, OUT, 0, 1048576, 256, nullptr, nullptr, smst, nullptr, nullptr);

        // MLPo = relu([OUT|Vcur] @ Wmlp^T + b)  [M=32768,N=512,K=512 split@256]
        gemm_bt<3, 3><<<dim3(4, 256, 1), 256, 0, stream>>>(
            OUT, Vcur, nullptr, 256, 256, 0, 256, Wm_b, 512, 0, 0, 0, 512, 1,
            nullptr, MLPo, 0, 0, 512, nullptr, bmlp, nullptr, nullptr, nullptr);

        // LN1024 stats
        stats1024_k<<<dim3(8192), 256, 0, stream>>>(OUT, Vcur, MLPo, lnst);

        // Tb = LN1024([OUT|Vcur|MLPo]) @ Wres^T + 2*Xb  [M=32768,N=256,K=1024]
        gemm_bt<4, 2><<<dim3(2, 256, 1), 256, 0, stream>>>(
            OUT, Vcur, MLPo, 256, 256, 512, 0, Wr_b, 1024, 0, 0, 0, 1024, 1,
            nullptr, Tb, 0, 0, 256, Xb, nullptr, lnst, g1, be1);

        // LN256 + transpose fused
        if (it == 0) {
            ln256t_k<u16, true><<<dim3(1024), 256, 0, stream>>>(
                Tb, g2, be2, Vb, VT2);
            VTcur = VT2;
            Vcur  = Vb;
        } else {
            ln256t_k<float, false><<<dim3(1024), 256, 0, stream>>>(
                Tb, g2, be2, nullptr, (float*)d_out);
        }
    }
}

// Round 8
// 410.167 us; speedup vs baseline: 1.0309x; 1.0309x over previous
//
#include <hip/hip_runtime.h>
#include <cstdint>
#include <cstddef>

// IT_Fast_Attn: B=8, C=256, N=4096, 2 iterations. fp32 I/O, bf16 compute.
// Round 8: gemm_bt 512 threads / 8 waves (4x2), wave = 32x64 (2x4 MFMA tiles).
// Same 128x128 block tile + grids -> same traffic; 2x resident waves/CU to
// hide the barrier drain + TRF staging chains (r7: all pipes <25%, grid-capped
// at 8 waves/CU). Keeps r7's softmax/LN1024-in-staging fusions.

using u16 = unsigned short;
using short8 = __attribute__((ext_vector_type(8))) short;
using bf16x8 = __attribute__((ext_vector_type(8))) __bf16;
using f32x4  = __attribute__((ext_vector_type(4))) float;
using i32x4  = __attribute__((ext_vector_type(4))) int;
using u16x4  = __attribute__((ext_vector_type(4))) u16;
using u16x8  = __attribute__((ext_vector_type(8))) u16;

__device__ __forceinline__ float b2f(u16 u) {
    union { unsigned u32; float f; } c; c.u32 = ((unsigned)u) << 16; return c.f;
}
__device__ __forceinline__ u16 f2b(float f) {
    union { float f; unsigned u; } c; c.f = f;
    unsigned r = c.u + 0x7FFFu + ((c.u >> 16) & 1u);
    return (u16)(r >> 16);
}
__device__ __forceinline__ void cvt(u16 a,  u16& o)   { o = a; }
__device__ __forceinline__ void cvt(float a, u16& o)  { o = f2b(a); }
__device__ __forceinline__ void cvt(float a, float& o){ o = a; }
__device__ __forceinline__ void cvt(u16 a,  float& o) { o = b2f(a); }

// ---------------------------------------------------------------------------
// BT GEMM: C[row,col] = sum_k A[row,k] * B[col,k].  BM=BN=128, BK=32.
// 512 threads = 8 waves in 4x2; wave covers 32 rows x 64 cols (2x4 tiles of
// 16x16x32 bf16 MFMA, acc 32 VGPR). COL-fastest grid (r3-measured L2 A-reuse).
// Staging: thread t loads one 8-elem A chunk (row=t>>2) + one B chunk.
// TRF: 0 plain | 1 softmax exp(a-st.x)*st.y | 2 LN1024 affine over A|A2|A3
//      (region=k>>8) | 3 two-source split at kSplit (no transform).
// MODE: 0 store bf16 | 1 fp32 partial per ks-slice | 3 +bias,relu,bf16
//       | 4 +2*Xres(bf16), bf16.
// ---------------------------------------------------------------------------
template<int MODE, int TRF>
__global__ __launch_bounds__(512)
void gemm_bt(const u16* __restrict__ A, const u16* __restrict__ A2,
             const u16* __restrict__ A3,
             int lda, int lda2, int lda3, int kSplit,
             const u16* __restrict__ B, int ldb, long strA, long strB,
             int statStride, int kChunk, int nKsplit,
             float* __restrict__ outF, u16* __restrict__ outB,
             long sOF, long sOB, int ldo,
             const u16* __restrict__ Xres,
             const float* __restrict__ bias,
             const float2* __restrict__ stats,
             const float* __restrict__ g, const float* __restrict__ be)
{
    __shared__ short lsA[128 * 40];
    __shared__ short lsB[128 * 40];

    const int bz    = blockIdx.z;
    const int batch = bz / nKsplit;
    const int ks    = bz - batch * nKsplit;
    const u16* Ab = A + (size_t)batch * strA;
    const u16* Bb = B + (size_t)batch * strB;
    const int colBase = blockIdx.x * 128;   // col-fastest
    const int rowBase = blockIdx.y * 128;
    const int k0 = ks * kChunk;
    const int k1 = k0 + kChunk;

    const int t    = threadIdx.x;
    const int sRow = t >> 2;           // 0..127
    const int sKq  = (t & 3) << 3;     // 0,8,16,24

    const int lane = t & 63;
    const int w    = t >> 6;           // 0..7
    const int wr   = (w >> 1) * 32;    // wave row base (4 rows of waves)
    const int wc   = (w & 1) * 64;     // wave col base (2 cols of waves)
    const int mrow = lane & 15;
    const int q    = lane >> 4;

    float2 st0 = {0.f, 0.f};
    if (TRF == 1 || TRF == 2)
        st0 = stats[batch * statStride + rowBase + sRow];

    // raw A load for staged row (rowBase + sRow) at k-base kn
    auto loadRaw = [&](int kn) -> i32x4 {
        const int arow = rowBase + sRow;
        if (TRF == 2) {
            const u16* s; int ld; int kl;
            const int reg = kn >> 8;
            if (reg == 0)      { s = A;  ld = lda;  kl = kn; }
            else if (reg == 1) { s = A2; ld = lda2; kl = kn - 256; }
            else               { s = A3; ld = lda3; kl = kn - 512; }
            return *(const i32x4*)(s + (size_t)arow * ld + kl + sKq);
        } else if (TRF == 3) {
            if (kn < kSplit)
                return *(const i32x4*)(Ab + (size_t)arow * lda + kn + sKq);
            return *(const i32x4*)(A2 + (size_t)arow * lda2 + (kn - kSplit) + sKq);
        }
        return *(const i32x4*)(Ab + (size_t)arow * lda + kn + sKq);
    };
    auto xform = [&](i32x4 raw, int kn) -> i32x4 {
        if (TRF == 0 || TRF == 3) return raw;
        short8 h = __builtin_bit_cast(short8, raw);
        short8 o;
#pragma unroll
        for (int i = 0; i < 8; i++) {
            float v = b2f((u16)h[i]);
            if (TRF == 1) v = __expf(v - st0.x) * st0.y;
            else          v = (v - st0.x) * st0.y * g[kn + sKq + i] + be[kn + sKq + i];
            o[i] = (short)f2b(v);
        }
        return __builtin_bit_cast(i32x4, o);
    };

    const f32x4 fzero = {0.f, 0.f, 0.f, 0.f};
    f32x4 acc[2][4];
#pragma unroll
    for (int i = 0; i < 2; i++)
#pragma unroll
        for (int j = 0; j < 4; j++) acc[i][j] = fzero;

    const u16* pB0 = Bb + (size_t)(colBase + sRow) * ldb + sKq;

    i32x4 a0 = xform(loadRaw(k0), k0);
    i32x4 b0 = *(const i32x4*)(pB0 + k0);

    for (int kk = k0; kk < k1; kk += 32) {
        __syncthreads();
        *(i32x4*)&lsA[sRow * 40 + sKq] = a0;
        *(i32x4*)&lsB[sRow * 40 + sKq] = b0;
        __syncthreads();
        const int kn = kk + 32;
        if (kn < k1) {
            a0 = xform(loadRaw(kn), kn);
            b0 = *(const i32x4*)(pB0 + kn);
        }
        bf16x8 af[2], bfr[4];
#pragma unroll
        for (int mi = 0; mi < 2; mi++)
            af[mi] = __builtin_bit_cast(bf16x8,
                *(const short8*)&lsA[(wr + mi * 16 + mrow) * 40 + q * 8]);
#pragma unroll
        for (int ni = 0; ni < 4; ni++)
            bfr[ni] = __builtin_bit_cast(bf16x8,
                *(const short8*)&lsB[(wc + ni * 16 + mrow) * 40 + q * 8]);
#pragma unroll
        for (int mi = 0; mi < 2; mi++)
#pragma unroll
            for (int ni = 0; ni < 4; ni++)
                acc[mi][ni] = __builtin_amdgcn_mfma_f32_16x16x32_bf16(
                    af[mi], bfr[ni], acc[mi][ni], 0, 0, 0);
    }

    // epilogue: lane holds D[row = q*4+r][col = mrow] per 16x16 tile
#pragma unroll
    for (int mi = 0; mi < 2; mi++) {
#pragma unroll
        for (int ni = 0; ni < 4; ni++) {
            const int col = colBase + wc + ni * 16 + mrow;
#pragma unroll
            for (int r = 0; r < 4; r++) {
                const int row = rowBase + wr + mi * 16 + q * 4 + r;
                float v = acc[mi][ni][r];
                if (MODE == 0) {
                    outB[(size_t)batch * sOB + (size_t)row * ldo + col] = f2b(v);
                } else if (MODE == 1) {
                    outF[((size_t)batch * nKsplit + ks) * sOF
                         + (size_t)row * ldo + col] = v;
                } else if (MODE == 3) {
                    v += bias[col];
                    v = v > 0.f ? v : 0.f;
                    outB[(size_t)row * ldo + col] = f2b(v);
                } else if (MODE == 4) {
                    v += 2.f * b2f(Xres[(size_t)row * 256 + col]);
                    outB[(size_t)row * ldo + col] = f2b(v);
                }
            }
        }
    }
}

// ---------------------------------------------------------------------------
// Transpose (R x Cc) -> (Cc x R) per batch, with dtype conversion.
// ---------------------------------------------------------------------------
template<typename TIN, typename TOUT>
__global__ __launch_bounds__(256)
void transpose_k(const TIN* __restrict__ in, TOUT* __restrict__ out,
                 int R, int Cc, long sIn, long sOut)
{
    __shared__ TOUT tile[32][33];
    const int b = blockIdx.z;
    const TIN* ib = in + (size_t)b * sIn;
    TOUT* ob = out + (size_t)b * sOut;
    const int c0 = blockIdx.x * 32, r0 = blockIdx.y * 32;
    const int tx = threadIdx.x & 31, ty = threadIdx.x >> 5;
#pragma unroll
    for (int i = 0; i < 32; i += 8)
        cvt(ib[(size_t)(r0 + ty + i) * Cc + c0 + tx], tile[ty + i][tx]);
    __syncthreads();
#pragma unroll
    for (int i = 0; i < 32; i += 8)
        ob[(size_t)(c0 + ty + i) * R + r0 + tx] = tile[tx][ty + i];
}

// Per-row softmax stats of Xb (rows of 256): {max, 1/sumexp}. One wave/row.
__global__ __launch_bounds__(256)
void smstats_k(const u16* __restrict__ Xb, float2* __restrict__ st)
{
    const int wave = threadIdx.x >> 6, lane = threadIdx.x & 63;
    const size_t row = (size_t)blockIdx.x * 4 + wave;
    const u16x4 xb = *(const u16x4*)(Xb + row * 256 + lane * 4);
    const float x0 = b2f(xb.x), x1 = b2f(xb.y), x2 = b2f(xb.z), x3 = b2f(xb.w);
    float m = fmaxf(fmaxf(x0, x1), fmaxf(x2, x3));
    for (int o = 32; o > 0; o >>= 1) m = fmaxf(m, __shfl_xor(m, o));
    float s = __expf(x0 - m) + __expf(x1 - m) + __expf(x2 - m) + __expf(x3 - m);
    for (int o = 32; o > 0; o >>= 1) s += __shfl_xor(s, o);
    if (lane == 0) st[row] = make_float2(m, 1.f / s);
}

// Per-row LN stats of virtual row [OUT(256)|V(256)|MLPo(512)]: {mean, rstd}.
__global__ __launch_bounds__(256)
void stats1024_k(const u16* __restrict__ OUT, const u16* __restrict__ V,
                 const u16* __restrict__ MLPo, float2* __restrict__ st)
{
    const int wave = threadIdx.x >> 6, lane = threadIdx.x & 63;
    const size_t row = (size_t)blockIdx.x * 4 + wave;
    const int c = lane * 16;
    const u16* src;
    if (c < 256)       src = OUT  + row * 256 + c;
    else if (c < 512)  src = V    + row * 256 + (c - 256);
    else               src = MLPo + row * 512 + (c - 512);
    short8 r0 = *(const short8*)(src);
    short8 r1 = *(const short8*)(src + 8);
    float s = 0.f, s2 = 0.f;
#pragma unroll
    for (int i = 0; i < 8; i++) {
        const float a = b2f((u16)r0[i]), b = b2f((u16)r1[i]);
        s += a + b; s2 += a * a + b * b;
    }
    for (int o = 32; o > 0; o >>= 1) { s += __shfl_xor(s, o); s2 += __shfl_xor(s2, o); }
    const float mean = s * (1.f / 1024.f);
    const float var  = s2 * (1.f / 1024.f) - mean * mean;
    if (lane == 0) st[row] = make_float2(mean, rsqrtf(var + 1e-5f));
}

// ---------------------------------------------------------------------------
// Fused LN256 + transpose (unchanged from r5).
// ---------------------------------------------------------------------------
template<typename OUTT, bool WRITE_VB>
__global__ __launch_bounds__(256)
void ln256t_k(const u16* __restrict__ Tb, const float* __restrict__ g,
              const float* __restrict__ be, u16* __restrict__ Vb,
              OUTT* __restrict__ outT)
{
    constexpr int STRIDE = (sizeof(OUTT) == 2) ? 266 : 261;
    __shared__ OUTT tile[32 * STRIDE];
    const int wid = threadIdx.x >> 6, lane = threadIdx.x & 63;
    const int bx = blockIdx.x;
    const size_t r0 = (size_t)bx * 32;
    const int b  = bx >> 7;
    const int n0 = (bx & 127) * 32;

#pragma unroll
    for (int j = 0; j < 8; j++) {
        const int lr = wid * 8 + j;
        const size_t row = r0 + lr;
        const u16x4 tb = *(const u16x4*)(Tb + row * 256 + lane * 4);
        const float x0 = b2f(tb.x), x1 = b2f(tb.y), x2 = b2f(tb.z), x3 = b2f(tb.w);
        float s  = x0 + x1 + x2 + x3;
        float s2 = x0 * x0 + x1 * x1 + x2 * x2 + x3 * x3;
        for (int o = 32; o > 0; o >>= 1) { s += __shfl_xor(s, o); s2 += __shfl_xor(s2, o); }
        const float mean = s * (1.f / 256.f);
        const float var  = s2 * (1.f / 256.f) - mean * mean;
        const float rstd = rsqrtf(var + 1e-5f);
        const int c = lane * 4;
        float4 ov = { (x0 - mean) * rstd * g[c + 0] + be[c + 0],
                      (x1 - mean) * rstd * g[c + 1] + be[c + 1],
                      (x2 - mean) * rstd * g[c + 2] + be[c + 2],
                      (x3 - mean) * rstd * g[c + 3] + be[c + 3] };
        if (WRITE_VB) {
            u16x4 vb = { f2b(ov.x), f2b(ov.y), f2b(ov.z), f2b(ov.w) };
            *(u16x4*)(Vb + row * 256 + c) = vb;
        }
        OUTT* tl = &tile[lr * STRIDE + c];
        cvt(ov.x, tl[0]); cvt(ov.y, tl[1]); cvt(ov.z, tl[2]); cvt(ov.w, tl[3]);
    }
    __syncthreads();

    const int c = threadIdx.x;
    OUTT* dst = outT + ((size_t)b * 256 + c) * 4096 + n0;
    if (sizeof(OUTT) == 2) {
#pragma unroll
        for (int k = 0; k < 4; k++) {
            u16x8 v;
#pragma unroll
            for (int i = 0; i < 8; i++) v[i] = *(const u16*)&tile[(k * 8 + i) * STRIDE + c];
            *(u16x8*)((u16*)dst + k * 8) = v;
        }
    } else {
#pragma unroll
        for (int k = 0; k < 8; k++) {
            float4 v;
            v.x = *(const float*)&tile[(k * 4 + 0) * STRIDE + c];
            v.y = *(const float*)&tile[(k * 4 + 1) * STRIDE + c];
            v.z = *(const float*)&tile[(k * 4 + 2) * STRIDE + c];
            v.w = *(const float*)&tile[(k * 4 + 3) * STRIDE + c];
            *(float4*)((float*)dst + k * 4) = v;
        }
    }
}

// Reduce 16 split-K partial fp32 ctx buffers -> bf16.
__global__ __launch_bounds__(256)
void ctxreduce_k(const float* __restrict__ ctxp, u16* __restrict__ ctxb)
{
    const int i = blockIdx.x * 256 + threadIdx.x;
    const int batch  = i >> 14;
    const int within = i & 16383;
    const float4* src = (const float4*)ctxp + (size_t)batch * 16 * 16384 + within;
    float4 s = {0.f, 0.f, 0.f, 0.f};
#pragma unroll
    for (int ks = 0; ks < 16; ks++) {
        const float4 v = src[(size_t)ks * 16384];
        s.x += v.x; s.y += v.y; s.z += v.z; s.w += v.w;
    }
    u16x4 o = { f2b(s.x), f2b(s.y), f2b(s.z), f2b(s.w) };
    ((u16x4*)ctxb)[i] = o;
}

// Convert three weight matrices fp32->bf16 in one launch.
__global__ __launch_bounds__(256)
void wconv_k(const float* __restrict__ Wq, const float* __restrict__ Wm,
             const float* __restrict__ Wr, u16* __restrict__ oq,
             u16* __restrict__ om, u16* __restrict__ orr)
{
    const int i = blockIdx.x * 256 + threadIdx.x;
    const float* src; u16* dst; int j;
    if (i < 16384)      { src = Wq; dst = oq;  j = i; }
    else if (i < 81920) { src = Wm; dst = om;  j = i - 16384; }
    else                { src = Wr; dst = orr; j = i - 81920; }
    const float4 v = ((const float4*)src)[j];
    u16x4 o = { f2b(v.x), f2b(v.y), f2b(v.z), f2b(v.w) };
    ((u16x4*)dst)[j] = o;
}

extern "C" void kernel_launch(void* const* d_in, const int* in_sizes, int n_in,
                              void* d_out, int out_size, void* d_ws, size_t ws_size,
                              hipStream_t stream)
{
    (void)in_sizes; (void)n_in; (void)out_size; (void)ws_size;
    const float* x    = (const float*)d_in[0];
    const float* Wqkv = (const float*)d_in[1];
    const float* Wmlp = (const float*)d_in[2];
    const float* bmlp = (const float*)d_in[3];
    const float* g1   = (const float*)d_in[4];
    const float* be1  = (const float*)d_in[5];
    const float* Wres = (const float*)d_in[6];
    const float* g2   = (const float*)d_in[7];
    const float* be2  = (const float*)d_in[8];

    // workspace (~172 MiB of 256)
    char* ws = (char*)d_ws;
    u16*    Xb   = (u16*)ws;    ws += (size_t)16777216;   // (32768,256)
    u16*    XT   = (u16*)ws;    ws += (size_t)16777216;   // (B,256,4096)
    u16*    Vb   = (u16*)ws;    ws += (size_t)16777216;   // (32768,256)
    u16*    VT2  = (u16*)ws;    ws += (size_t)16777216;   // (B,256,4096)
    u16*    OUT  = (u16*)ws;    ws += (size_t)16777216;   // (32768,256)
    u16*    MLPo = (u16*)ws;    ws += (size_t)33554432;   // (32768,512)
    u16*    Tb   = (u16*)ws;    ws += (size_t)16777216;   // (32768,256)
    float*  ctxp = (float*)ws;  ws += (size_t)33554432;   // (B*16,256,256) fp32
    u16*    ctxb = (u16*)ws;    ws += (size_t)1048576;    // (B,256,256)
    float2* smst = (float2*)ws; ws += (size_t)262144;     // (32768) {max,1/s}
    float2* lnst = (float2*)ws; ws += (size_t)262144;     // (32768) {mean,rstd}
    u16*    Wq_b = (u16*)ws;    ws += (size_t)131072;
    u16*    Wm_b = (u16*)ws;    ws += (size_t)524288;
    u16*    Wr_b = (u16*)ws;    ws += (size_t)524288;
    u16*    xt   = MLPo;  // alias: xt dead before MLPo's first write

    // 0. weights fp32 -> bf16
    wconv_k<<<dim3(576), 256, 0, stream>>>(Wqkv, Wmlp, Wres, Wq_b, Wm_b, Wr_b);

    // 1. xt = transpose(x): per batch (256,4096) fp32 -> (4096,256) bf16
    transpose_k<float, u16><<<dim3(128, 8, 8), 256, 0, stream>>>(
        x, xt, 256, 4096, 256L * 4096, 4096L * 256);

    // 2. Xb = xt @ Wqkv^T   [M=32768,N=256,K=256]
    gemm_bt<0, 0><<<dim3(2, 256, 1), 512, 0, stream>>>(
        xt, nullptr, nullptr, 256, 0, 0, 0, Wq_b, 256, 0, 0, 0, 256, 1,
        nullptr, Xb, 0, 0, 256, nullptr, nullptr, nullptr, nullptr, nullptr);

    // 3. XT = transpose(Xb)
    transpose_k<u16, u16><<<dim3(8, 128, 8), 256, 0, stream>>>(
        Xb, XT, 4096, 256, 4096L * 256, 256L * 4096);

    const u16* VTcur = XT;
    const u16* Vcur  = Xb;

    for (int it = 0; it < 2; ++it) {
        // softmax stats
        smstats_k<<<dim3(8192), 256, 0, stream>>>(Xb, smst);

        // ctx split-K=16 partials
        gemm_bt<1, 0><<<dim3(2, 2, 128), 512, 0, stream>>>(
            VTcur, nullptr, nullptr, 4096, 0, 0, 0, XT, 4096,
            1048576, 1048576, 0, 256, 16,
            ctxp, nullptr, 65536, 0, 256, nullptr, nullptr, nullptr, nullptr, nullptr);
        ctxreduce_k<<<dim3(512), 256, 0, stream>>>(ctxp, ctxb);

        // OUT = softmax(Xb) @ ctxT^T  (exp in staging) [per batch 4096x256,K=256]
        gemm_bt<0, 1><<<dim3(2, 32, 8), 512, 0, stream>>>(
            Xb, nullptr, nullptr, 256, 0, 0, 0, ctxb, 256,
            1048576, 65536, 4096, 256, 1,
            nullptr, OUT, 0, 1048576, 256, nullptr, nullptr, smst, nullptr, nullptr);

        // MLPo = relu([OUT|Vcur] @ Wmlp^T + b)  [M=32768,N=512,K=512 split@256]
        gemm_bt<3, 3><<<dim3(4, 256, 1), 512, 0, stream>>>(
            OUT, Vcur, nullptr, 256, 256, 0, 256, Wm_b, 512, 0, 0, 0, 512, 1,
            nullptr, MLPo, 0, 0, 512, nullptr, bmlp, nullptr, nullptr, nullptr);

        // LN1024 stats
        stats1024_k<<<dim3(8192), 256, 0, stream>>>(OUT, Vcur, MLPo, lnst);

        // Tb = LN1024([OUT|Vcur|MLPo]) @ Wres^T + 2*Xb  [M=32768,N=256,K=1024]
        gemm_bt<4, 2><<<dim3(2, 256, 1), 512, 0, stream>>>(
            OUT, Vcur, MLPo, 256, 256, 512, 0, Wr_b, 1024, 0, 0, 0, 1024, 1,
            nullptr, Tb, 0, 0, 256, Xb, nullptr, lnst, g1, be1);

        // LN256 + transpose fused
        if (it == 0) {
            ln256t_k<u16, true><<<dim3(1024), 256, 0, stream>>>(
                Tb, g2, be2, Vb, VT2);
            VTcur = VT2;
            Vcur  = Vb;
        } else {
            ln256t_k<float, false><<<dim3(1024), 256, 0, stream>>>(
                Tb, g2, be2, nullptr, (float*)d_out);
        }
    }
}

// Round 9
// 387.278 us; speedup vs baseline: 1.0918x; 1.0591x over previous
//
#include <hip/hip_runtime.h>
#include <cstdint>
#include <cstddef>

// IT_Fast_Attn: B=8, C=256, N=4096, 2 iterations. fp32 I/O, bf16 compute.
// Round 9: BK=64 k-loop (half the barrier drains, 4 loads in flight/thread,
// 16 MFMAs between barriers per wave). r8 showed occupancy-doubling didn't
// move the needle -> limiter is per-iter serial structure, not wave count.
// LDS stride 72 shorts (36-bank row offset -> 2-way conflicts, free).

using u16 = unsigned short;
using short8 = __attribute__((ext_vector_type(8))) short;
using bf16x8 = __attribute__((ext_vector_type(8))) __bf16;
using f32x4  = __attribute__((ext_vector_type(4))) float;
using i32x4  = __attribute__((ext_vector_type(4))) int;
using u16x4  = __attribute__((ext_vector_type(4))) u16;
using u16x8  = __attribute__((ext_vector_type(8))) u16;

__device__ __forceinline__ float b2f(u16 u) {
    union { unsigned u32; float f; } c; c.u32 = ((unsigned)u) << 16; return c.f;
}
__device__ __forceinline__ u16 f2b(float f) {
    union { float f; unsigned u; } c; c.f = f;
    unsigned r = c.u + 0x7FFFu + ((c.u >> 16) & 1u);
    return (u16)(r >> 16);
}
__device__ __forceinline__ void cvt(u16 a,  u16& o)   { o = a; }
__device__ __forceinline__ void cvt(float a, u16& o)  { o = f2b(a); }
__device__ __forceinline__ void cvt(float a, float& o){ o = a; }
__device__ __forceinline__ void cvt(u16 a,  float& o) { o = b2f(a); }

// ---------------------------------------------------------------------------
// BT GEMM: C[row,col] = sum_k A[row,k] * B[col,k].  BM=BN=128, BK=64.
// 512 threads = 8 waves in 4x2; wave covers 32 rows x 64 cols; 16 MFMAs/iter
// (2 mi x 4 ni x 2 k-halves of 16x16x32 bf16). COL-fastest grid (L2 A-reuse).
// Staging: thread t loads rows (t>>3) and (t>>3)+64, 8-elem chunk (t&7)*8;
// 4 global loads in flight per thread per iter.
// TRF: 0 plain | 1 softmax exp(a-st.x)*st.y | 2 LN1024 affine over A|A2|A3
//      (region=k>>8; BK=64 divides 256 so a chunk never crosses regions)
//      | 3 two-source split at kSplit (no transform).
// MODE: 0 store bf16 | 1 fp32 partial per ks-slice | 3 +bias,relu,bf16
//       | 4 +2*Xres(bf16), bf16.
// ---------------------------------------------------------------------------
template<int MODE, int TRF>
__global__ __launch_bounds__(512)
void gemm_bt(const u16* __restrict__ A, const u16* __restrict__ A2,
             const u16* __restrict__ A3,
             int lda, int lda2, int lda3, int kSplit,
             const u16* __restrict__ B, int ldb, long strA, long strB,
             int statStride, int kChunk, int nKsplit,
             float* __restrict__ outF, u16* __restrict__ outB,
             long sOF, long sOB, int ldo,
             const u16* __restrict__ Xres,
             const float* __restrict__ bias,
             const float2* __restrict__ stats,
             const float* __restrict__ g, const float* __restrict__ be)
{
    __shared__ short lsA[128 * 72];
    __shared__ short lsB[128 * 72];

    const int bz    = blockIdx.z;
    const int batch = bz / nKsplit;
    const int ks    = bz - batch * nKsplit;
    const u16* Ab = A + (size_t)batch * strA;
    const u16* Bb = B + (size_t)batch * strB;
    const int colBase = blockIdx.x * 128;   // col-fastest
    const int rowBase = blockIdx.y * 128;
    const int k0 = ks * kChunk;
    const int k1 = k0 + kChunk;

    const int t    = threadIdx.x;
    const int sRow = t >> 3;           // 0..63
    const int sKq  = (t & 7) << 3;     // 0,8,...,56

    const int lane = t & 63;
    const int w    = t >> 6;           // 0..7
    const int wr   = (w >> 1) * 32;    // wave row base
    const int wc   = (w & 1) * 64;     // wave col base
    const int mrow = lane & 15;
    const int q    = lane >> 4;

    float2 st0 = {0.f, 0.f}, st1 = {0.f, 0.f};
    if (TRF == 1 || TRF == 2) {
        const int sb = batch * statStride + rowBase;
        st0 = stats[sb + sRow];
        st1 = stats[sb + sRow + 64];
    }

    // raw A load for staged row (rowBase + rloc + sRow) at k-base kn (64-mult)
    auto loadRaw = [&](int rloc, int kn) -> i32x4 {
        const int arow = rowBase + rloc + sRow;
        if (TRF == 2) {
            const u16* s; int ld; int kl;
            const int kc = kn + sKq;          // chunk k (regions 256-aligned)
            const int reg = kc >> 8;
            if (reg == 0)      { s = A;  ld = lda;  kl = kc; }
            else if (reg == 1) { s = A2; ld = lda2; kl = kc - 256; }
            else               { s = A3; ld = lda3; kl = kc - 512; }
            return *(const i32x4*)(s + (size_t)arow * ld + kl);
        } else if (TRF == 3) {
            const int kc = kn + sKq;
            if (kc < kSplit)
                return *(const i32x4*)(Ab + (size_t)arow * lda + kc);
            return *(const i32x4*)(A2 + (size_t)arow * lda2 + (kc - kSplit));
        }
        return *(const i32x4*)(Ab + (size_t)arow * lda + kn + sKq);
    };
    auto xform = [&](i32x4 raw, float2 st, int kn) -> i32x4 {
        if (TRF == 0 || TRF == 3) return raw;
        short8 h = __builtin_bit_cast(short8, raw);
        short8 o;
#pragma unroll
        for (int i = 0; i < 8; i++) {
            float v = b2f((u16)h[i]);
            if (TRF == 1) v = __expf(v - st.x) * st.y;
            else          v = (v - st.x) * st.y * g[kn + sKq + i] + be[kn + sKq + i];
            o[i] = (short)f2b(v);
        }
        return __builtin_bit_cast(i32x4, o);
    };

    const f32x4 fzero = {0.f, 0.f, 0.f, 0.f};
    f32x4 acc[2][4];
#pragma unroll
    for (int i = 0; i < 2; i++)
#pragma unroll
        for (int j = 0; j < 4; j++) acc[i][j] = fzero;

    const u16* pB0 = Bb + (size_t)(colBase + sRow) * ldb + sKq;
    const u16* pB1 = pB0 + (size_t)64 * ldb;

    i32x4 a0 = xform(loadRaw(0,  k0), st0, k0);
    i32x4 a1 = xform(loadRaw(64, k0), st1, k0);
    i32x4 b0 = *(const i32x4*)(pB0 + k0);
    i32x4 b1 = *(const i32x4*)(pB1 + k0);

    for (int kk = k0; kk < k1; kk += 64) {
        __syncthreads();
        *(i32x4*)&lsA[sRow * 72 + sKq]        = a0;
        *(i32x4*)&lsA[(sRow + 64) * 72 + sKq] = a1;
        *(i32x4*)&lsB[sRow * 72 + sKq]        = b0;
        *(i32x4*)&lsB[(sRow + 64) * 72 + sKq] = b1;
        __syncthreads();
        const int kn = kk + 64;
        if (kn < k1) {
            a0 = xform(loadRaw(0,  kn), st0, kn);
            a1 = xform(loadRaw(64, kn), st1, kn);
            b0 = *(const i32x4*)(pB0 + kn);
            b1 = *(const i32x4*)(pB1 + kn);
        }
#pragma unroll
        for (int h = 0; h < 2; h++) {
            bf16x8 af[2], bfr[4];
#pragma unroll
            for (int mi = 0; mi < 2; mi++)
                af[mi] = __builtin_bit_cast(bf16x8,
                    *(const short8*)&lsA[(wr + mi * 16 + mrow) * 72 + h * 32 + q * 8]);
#pragma unroll
            for (int ni = 0; ni < 4; ni++)
                bfr[ni] = __builtin_bit_cast(bf16x8,
                    *(const short8*)&lsB[(wc + ni * 16 + mrow) * 72 + h * 32 + q * 8]);
#pragma unroll
            for (int mi = 0; mi < 2; mi++)
#pragma unroll
                for (int ni = 0; ni < 4; ni++)
                    acc[mi][ni] = __builtin_amdgcn_mfma_f32_16x16x32_bf16(
                        af[mi], bfr[ni], acc[mi][ni], 0, 0, 0);
        }
    }

    // epilogue: lane holds D[row = q*4+r][col = mrow] per 16x16 tile
#pragma unroll
    for (int mi = 0; mi < 2; mi++) {
#pragma unroll
        for (int ni = 0; ni < 4; ni++) {
            const int col = colBase + wc + ni * 16 + mrow;
#pragma unroll
            for (int r = 0; r < 4; r++) {
                const int row = rowBase + wr + mi * 16 + q * 4 + r;
                float v = acc[mi][ni][r];
                if (MODE == 0) {
                    outB[(size_t)batch * sOB + (size_t)row * ldo + col] = f2b(v);
                } else if (MODE == 1) {
                    outF[((size_t)batch * nKsplit + ks) * sOF
                         + (size_t)row * ldo + col] = v;
                } else if (MODE == 3) {
                    v += bias[col];
                    v = v > 0.f ? v : 0.f;
                    outB[(size_t)row * ldo + col] = f2b(v);
                } else if (MODE == 4) {
                    v += 2.f * b2f(Xres[(size_t)row * 256 + col]);
                    outB[(size_t)row * ldo + col] = f2b(v);
                }
            }
        }
    }
}

// ---------------------------------------------------------------------------
// Transpose (R x Cc) -> (Cc x R) per batch, with dtype conversion.
// ---------------------------------------------------------------------------
template<typename TIN, typename TOUT>
__global__ __launch_bounds__(256)
void transpose_k(const TIN* __restrict__ in, TOUT* __restrict__ out,
                 int R, int Cc, long sIn, long sOut)
{
    __shared__ TOUT tile[32][33];
    const int b = blockIdx.z;
    const TIN* ib = in + (size_t)b * sIn;
    TOUT* ob = out + (size_t)b * sOut;
    const int c0 = blockIdx.x * 32, r0 = blockIdx.y * 32;
    const int tx = threadIdx.x & 31, ty = threadIdx.x >> 5;
#pragma unroll
    for (int i = 0; i < 32; i += 8)
        cvt(ib[(size_t)(r0 + ty + i) * Cc + c0 + tx], tile[ty + i][tx]);
    __syncthreads();
#pragma unroll
    for (int i = 0; i < 32; i += 8)
        ob[(size_t)(c0 + ty + i) * R + r0 + tx] = tile[tx][ty + i];
}

// Per-row softmax stats of Xb (rows of 256): {max, 1/sumexp}. One wave/row.
__global__ __launch_bounds__(256)
void smstats_k(const u16* __restrict__ Xb, float2* __restrict__ st)
{
    const int wave = threadIdx.x >> 6, lane = threadIdx.x & 63;
    const size_t row = (size_t)blockIdx.x * 4 + wave;
    const u16x4 xb = *(const u16x4*)(Xb + row * 256 + lane * 4);
    const float x0 = b2f(xb.x), x1 = b2f(xb.y), x2 = b2f(xb.z), x3 = b2f(xb.w);
    float m = fmaxf(fmaxf(x0, x1), fmaxf(x2, x3));
    for (int o = 32; o > 0; o >>= 1) m = fmaxf(m, __shfl_xor(m, o));
    float s = __expf(x0 - m) + __expf(x1 - m) + __expf(x2 - m) + __expf(x3 - m);
    for (int o = 32; o > 0; o >>= 1) s += __shfl_xor(s, o);
    if (lane == 0) st[row] = make_float2(m, 1.f / s);
}

// Per-row LN stats of virtual row [OUT(256)|V(256)|MLPo(512)]: {mean, rstd}.
__global__ __launch_bounds__(256)
void stats1024_k(const u16* __restrict__ OUT, const u16* __restrict__ V,
                 const u16* __restrict__ MLPo, float2* __restrict__ st)
{
    const int wave = threadIdx.x >> 6, lane = threadIdx.x & 63;
    const size_t row = (size_t)blockIdx.x * 4 + wave;
    const int c = lane * 16;
    const u16* src;
    if (c < 256)       src = OUT  + row * 256 + c;
    else if (c < 512)  src = V    + row * 256 + (c - 256);
    else               src = MLPo + row * 512 + (c - 512);
    short8 r0 = *(const short8*)(src);
    short8 r1 = *(const short8*)(src + 8);
    float s = 0.f, s2 = 0.f;
#pragma unroll
    for (int i = 0; i < 8; i++) {
        const float a = b2f((u16)r0[i]), b = b2f((u16)r1[i]);
        s += a + b; s2 += a * a + b * b;
    }
    for (int o = 32; o > 0; o >>= 1) { s += __shfl_xor(s, o); s2 += __shfl_xor(s2, o); }
    const float mean = s * (1.f / 1024.f);
    const float var  = s2 * (1.f / 1024.f) - mean * mean;
    if (lane == 0) st[row] = make_float2(mean, rsqrtf(var + 1e-5f));
}

// ---------------------------------------------------------------------------
// Fused LN256 + transpose (unchanged from r5).
// ---------------------------------------------------------------------------
template<typename OUTT, bool WRITE_VB>
__global__ __launch_bounds__(256)
void ln256t_k(const u16* __restrict__ Tb, const float* __restrict__ g,
              const float* __restrict__ be, u16* __restrict__ Vb,
              OUTT* __restrict__ outT)
{
    constexpr int STRIDE = (sizeof(OUTT) == 2) ? 266 : 261;
    __shared__ OUTT tile[32 * STRIDE];
    const int wid = threadIdx.x >> 6, lane = threadIdx.x & 63;
    const int bx = blockIdx.x;
    const size_t r0 = (size_t)bx * 32;
    const int b  = bx >> 7;
    const int n0 = (bx & 127) * 32;

#pragma unroll
    for (int j = 0; j < 8; j++) {
        const int lr = wid * 8 + j;
        const size_t row = r0 + lr;
        const u16x4 tb = *(const u16x4*)(Tb + row * 256 + lane * 4);
        const float x0 = b2f(tb.x), x1 = b2f(tb.y), x2 = b2f(tb.z), x3 = b2f(tb.w);
        float s  = x0 + x1 + x2 + x3;
        float s2 = x0 * x0 + x1 * x1 + x2 * x2 + x3 * x3;
        for (int o = 32; o > 0; o >>= 1) { s += __shfl_xor(s, o); s2 += __shfl_xor(s2, o); }
        const float mean = s * (1.f / 256.f);
        const float var  = s2 * (1.f / 256.f) - mean * mean;
        const float rstd = rsqrtf(var + 1e-5f);
        const int c = lane * 4;
        float4 ov = { (x0 - mean) * rstd * g[c + 0] + be[c + 0],
                      (x1 - mean) * rstd * g[c + 1] + be[c + 1],
                      (x2 - mean) * rstd * g[c + 2] + be[c + 2],
                      (x3 - mean) * rstd * g[c + 3] + be[c + 3] };
        if (WRITE_VB) {
            u16x4 vb = { f2b(ov.x), f2b(ov.y), f2b(ov.z), f2b(ov.w) };
            *(u16x4*)(Vb + row * 256 + c) = vb;
        }
        OUTT* tl = &tile[lr * STRIDE + c];
        cvt(ov.x, tl[0]); cvt(ov.y, tl[1]); cvt(ov.z, tl[2]); cvt(ov.w, tl[3]);
    }
    __syncthreads();

    const int c = threadIdx.x;
    OUTT* dst = outT + ((size_t)b * 256 + c) * 4096 + n0;
    if (sizeof(OUTT) == 2) {
#pragma unroll
        for (int k = 0; k < 4; k++) {
            u16x8 v;
#pragma unroll
            for (int i = 0; i < 8; i++) v[i] = *(const u16*)&tile[(k * 8 + i) * STRIDE + c];
            *(u16x8*)((u16*)dst + k * 8) = v;
        }
    } else {
#pragma unroll
        for (int k = 0; k < 8; k++) {
            float4 v;
            v.x = *(const float*)&tile[(k * 4 + 0) * STRIDE + c];
            v.y = *(const float*)&tile[(k * 4 + 1) * STRIDE + c];
            v.z = *(const float*)&tile[(k * 4 + 2) * STRIDE + c];
            v.w = *(const float*)&tile[(k * 4 + 3) * STRIDE + c];
            *(float4*)((float*)dst + k * 4) = v;
        }
    }
}

// Reduce 16 split-K partial fp32 ctx buffers -> bf16.
__global__ __launch_bounds__(256)
void ctxreduce_k(const float* __restrict__ ctxp, u16* __restrict__ ctxb)
{
    const int i = blockIdx.x * 256 + threadIdx.x;
    const int batch  = i >> 14;
    const int within = i & 16383;
    const float4* src = (const float4*)ctxp + (size_t)batch * 16 * 16384 + within;
    float4 s = {0.f, 0.f, 0.f, 0.f};
#pragma unroll
    for (int ks = 0; ks < 16; ks++) {
        const float4 v = src[(size_t)ks * 16384];
        s.x += v.x; s.y += v.y; s.z += v.z; s.w += v.w;
    }
    u16x4 o = { f2b(s.x), f2b(s.y), f2b(s.z), f2b(s.w) };
    ((u16x4*)ctxb)[i] = o;
}

// Convert three weight matrices fp32->bf16 in one launch.
__global__ __launch_bounds__(256)
void wconv_k(const float* __restrict__ Wq, const float* __restrict__ Wm,
             const float* __restrict__ Wr, u16* __restrict__ oq,
             u16* __restrict__ om, u16* __restrict__ orr)
{
    const int i = blockIdx.x * 256 + threadIdx.x;
    const float* src; u16* dst; int j;
    if (i < 16384)      { src = Wq; dst = oq;  j = i; }
    else if (i < 81920) { src = Wm; dst = om;  j = i - 16384; }
    else                { src = Wr; dst = orr; j = i - 81920; }
    const float4 v = ((const float4*)src)[j];
    u16x4 o = { f2b(v.x), f2b(v.y), f2b(v.z), f2b(v.w) };
    ((u16x4*)dst)[j] = o;
}

extern "C" void kernel_launch(void* const* d_in, const int* in_sizes, int n_in,
                              void* d_out, int out_size, void* d_ws, size_t ws_size,
                              hipStream_t stream)
{
    (void)in_sizes; (void)n_in; (void)out_size; (void)ws_size;
    const float* x    = (const float*)d_in[0];
    const float* Wqkv = (const float*)d_in[1];
    const float* Wmlp = (const float*)d_in[2];
    const float* bmlp = (const float*)d_in[3];
    const float* g1   = (const float*)d_in[4];
    const float* be1  = (const float*)d_in[5];
    const float* Wres = (const float*)d_in[6];
    const float* g2   = (const float*)d_in[7];
    const float* be2  = (const float*)d_in[8];

    // workspace (~172 MiB of 256)
    char* ws = (char*)d_ws;
    u16*    Xb   = (u16*)ws;    ws += (size_t)16777216;   // (32768,256)
    u16*    XT   = (u16*)ws;    ws += (size_t)16777216;   // (B,256,4096)
    u16*    Vb   = (u16*)ws;    ws += (size_t)16777216;   // (32768,256)
    u16*    VT2  = (u16*)ws;    ws += (size_t)16777216;   // (B,256,4096)
    u16*    OUT  = (u16*)ws;    ws += (size_t)16777216;   // (32768,256)
    u16*    MLPo = (u16*)ws;    ws += (size_t)33554432;   // (32768,512)
    u16*    Tb   = (u16*)ws;    ws += (size_t)16777216;   // (32768,256)
    float*  ctxp = (float*)ws;  ws += (size_t)33554432;   // (B*16,256,256) fp32
    u16*    ctxb = (u16*)ws;    ws += (size_t)1048576;    // (B,256,256)
    float2* smst = (float2*)ws; ws += (size_t)262144;     // (32768) {max,1/s}
    float2* lnst = (float2*)ws; ws += (size_t)262144;     // (32768) {mean,rstd}
    u16*    Wq_b = (u16*)ws;    ws += (size_t)131072;
    u16*    Wm_b = (u16*)ws;    ws += (size_t)524288;
    u16*    Wr_b = (u16*)ws;    ws += (size_t)524288;
    u16*    xt   = MLPo;  // alias: xt dead before MLPo's first write

    // 0. weights fp32 -> bf16
    wconv_k<<<dim3(576), 256, 0, stream>>>(Wqkv, Wmlp, Wres, Wq_b, Wm_b, Wr_b);

    // 1. xt = transpose(x): per batch (256,4096) fp32 -> (4096,256) bf16
    transpose_k<float, u16><<<dim3(128, 8, 8), 256, 0, stream>>>(
        x, xt, 256, 4096, 256L * 4096, 4096L * 256);

    // 2. Xb = xt @ Wqkv^T   [M=32768,N=256,K=256]
    gemm_bt<0, 0><<<dim3(2, 256, 1), 512, 0, stream>>>(
        xt, nullptr, nullptr, 256, 0, 0, 0, Wq_b, 256, 0, 0, 0, 256, 1,
        nullptr, Xb, 0, 0, 256, nullptr, nullptr, nullptr, nullptr, nullptr);

    // 3. XT = transpose(Xb)
    transpose_k<u16, u16><<<dim3(8, 128, 8), 256, 0, stream>>>(
        Xb, XT, 4096, 256, 4096L * 256, 256L * 4096);

    const u16* VTcur = XT;
    const u16* Vcur  = Xb;

    for (int it = 0; it < 2; ++it) {
        // softmax stats
        smstats_k<<<dim3(8192), 256, 0, stream>>>(Xb, smst);

        // ctx split-K=16 partials
        gemm_bt<1, 0><<<dim3(2, 2, 128), 512, 0, stream>>>(
            VTcur, nullptr, nullptr, 4096, 0, 0, 0, XT, 4096,
            1048576, 1048576, 0, 256, 16,
            ctxp, nullptr, 65536, 0, 256, nullptr, nullptr, nullptr, nullptr, nullptr);
        ctxreduce_k<<<dim3(512), 256, 0, stream>>>(ctxp, ctxb);

        // OUT = softmax(Xb) @ ctxT^T  (exp in staging) [per batch 4096x256,K=256]
        gemm_bt<0, 1><<<dim3(2, 32, 8), 512, 0, stream>>>(
            Xb, nullptr, nullptr, 256, 0, 0, 0, ctxb, 256,
            1048576, 65536, 4096, 256, 1,
            nullptr, OUT, 0, 1048576, 256, nullptr, nullptr, smst, nullptr, nullptr);

        // MLPo = relu([OUT|Vcur] @ Wmlp^T + b)  [M=32768,N=512,K=512 split@256]
        gemm_bt<3, 3><<<dim3(4, 256, 1), 512, 0, stream>>>(
            OUT, Vcur, nullptr, 256, 256, 0, 256, Wm_b, 512, 0, 0, 0, 512, 1,
            nullptr, MLPo, 0, 0, 512, nullptr, bmlp, nullptr, nullptr, nullptr);

        // LN1024 stats
        stats1024_k<<<dim3(8192), 256, 0, stream>>>(OUT, Vcur, MLPo, lnst);

        // Tb = LN1024([OUT|Vcur|MLPo]) @ Wres^T + 2*Xb  [M=32768,N=256,K=1024]
        gemm_bt<4, 2><<<dim3(2, 256, 1), 512, 0, stream>>>(
            OUT, Vcur, MLPo, 256, 256, 512, 0, Wr_b, 1024, 0, 0, 0, 1024, 1,
            nullptr, Tb, 0, 0, 256, Xb, nullptr, lnst, g1, be1);

        // LN256 + transpose fused
        if (it == 0) {
            ln256t_k<u16, true><<<dim3(1024), 256, 0, stream>>>(
                Tb, g2, be2, Vb, VT2);
            VTcur = VT2;
            Vcur  = Vb;
        } else {
            ln256t_k<float, false><<<dim3(1024), 256, 0, stream>>>(
                Tb, g2, be2, nullptr, (float*)d_out);
        }
    }
}